// Round 4
// baseline (203.968 us; speedup 1.0000x reference)
//
#include <hip/hip_runtime.h>
#include <cmath>
#include <complex>

#define FEAT 576
#define BT 16       // batch rows per block
#define P1 18       // x1buf feat-row stride (f16) — keeps 4B alignment for f16x2 reads
#define P2 17       // x2buf feat-row stride (f16)

typedef _Float16 f16;
typedef _Float16 f16x2 __attribute__((ext_vector_type(2)));
typedef _Float16 f16x8 __attribute__((ext_vector_type(8)));
typedef float f32x4 __attribute__((ext_vector_type(4)));

struct KC { float c[363]; };

// pack two f32 -> f16x2 with one v_cvt_pkrtz (bit_cast bridges __fp16/_Float16 vec types)
__device__ __forceinline__ f16x2 pkrtz(float a, float b) {
  auto t = __builtin_amdgcn_cvt_pkrtz(a, b);
  return __builtin_bit_cast(f16x2, t);
}

// ---------------- Wigner-3j nonzero patterns (compile-time) ----------------
__host__ __device__ constexpr bool nz112(int i, int j, int k) {
  return (k == 0) ? ((i == 2 && j == 0) || (i == 0 && j == 2))
       : (k == 1) ? ((i == 0 && j == 1) || (i == 1 && j == 0))
       : (k == 2) ? (i == j)
       : (k == 3) ? ((i == 1 && j == 2) || (i == 2 && j == 1))
       :            ((i == 0 && j == 0) || (i == 2 && j == 2));
}
__host__ __device__ constexpr bool nz222(int i, int j, int k) {
  return (k == 0) ? ((i == 1 && j == 3) || (i == 3 && j == 1) || (i == 0 && j == 2) || (i == 2 && j == 0))
       : (k == 1) ? ((i == 0 && j == 3) || (i == 3 && j == 0) || (i == 1 && j == 2) || (i == 2 && j == 1) || (i == 1 && j == 4) || (i == 4 && j == 1))
       : (k == 2) ? (i == j)
       : (k == 3) ? ((i == 0 && j == 1) || (i == 1 && j == 0) || (i == 3 && j == 2) || (i == 2 && j == 3) || (i == 3 && j == 4) || (i == 4 && j == 3))
       :            ((i == 1 && j == 1) || (i == 3 && j == 3) || (i == 2 && j == 4) || (i == 4 && j == 2));
}
__host__ __device__ constexpr bool w3j_nz(int l1, int l2, int l3, int i, int j, int k) {
  return (l1 == 0) ? (j == k)
       : (l2 == 0) ? (i == k)
       : (l3 == 0) ? (i == j)
       : (l1 == 1 && l2 == 1 && l3 == 2) ? nz112(i, j, k)
       : (l1 == 1 && l2 == 2 && l3 == 1) ? nz112(i, k, j)
       : (l1 == 2 && l2 == 1 && l3 == 1) ? nz112(j, k, i)
       : nz222(i, j, k);
}
__host__ __device__ constexpr bool pair_used(int l1, int l2, int l3, int i, int j) {
  for (int k = 0; k < 2 * l3 + 1; ++k)
    if (w3j_nz(l1, l2, l3, i, j, k)) return true;
  return false;
}

// ---------------- prep: ws f32 -> f16 in MFMA B-fragment order ----------------
// wsf[((p*4 + nt)*128 + uk)*512 + lane*8 + j] = ws[p][uv = uk*32 + (lane>>4)*8 + j][w = nt*16 + (lane&15)]
__global__ void prep_ws(const float* __restrict__ ws, f16* __restrict__ wsf) {
  int blk = blockIdx.x;            // 11*128 blocks
  int p = blk >> 7, uk = blk & 127;
  int tid = threadIdx.x;           // 256
  int nt = tid >> 6, l = tid & 63;
  int w = nt * 16 + (l & 15);
  int uvb = uk * 32 + (l >> 4) * 8;
  f16x8 v;
#pragma unroll
  for (int j = 0; j < 8; ++j)
    v[j] = (f16)ws[(size_t)p * 262144 + (size_t)(uvb + j) * 64 + w];
  *(f16x8*)(wsf + ((size_t)((p * 4 + nt) * 128 + uk)) * 512 + (size_t)l * 8) = v;
}

// ---------------- main kernel ----------------
__device__ __forceinline__ f32x4 mfma16(f16x8 a, f16x8 b, f32x4 c) {
  return __builtin_amdgcn_mfma_f32_16x16x32_f16(a, b, c, 0, 0, 0);
}

template <int L1, int L2, int L3, int PORIG, int COFF, int J0, int JW>
__device__ __forceinline__ void run_chunk(
    const f16* __restrict__ x2buf, const f16* __restrict__ x1buf,
    const f16* __restrict__ wsf, const KC& kc,
    int lane, int nt, int uq, f32x4 (&o)[5]) {
  constexpr int d1 = 2 * L1 + 1, d2 = 2 * L2 + 1, d3 = 2 * L3 + 1;
  constexpr int OFF1 = (L1 == 0) ? 0 : (L1 == 1) ? 64 : 256;
  constexpr int OFF2 = (L2 == 0) ? 0 : (L2 == 1) ? 64 : 256;
  const int brow = lane >> 4, bcol = lane & 15;

  // pack A-fragments (x2) for jj in [J0, J0+JW); A row m = bcol (b), k = v
  f16x8 afrag[JW][2];
#pragma unroll
  for (int jw = 0; jw < JW; ++jw)
#pragma unroll
    for (int ks = 0; ks < 2; ++ks)
#pragma unroll
      for (int j = 0; j < 8; ++j) {
        int v = ks * 32 + brow * 8 + j;
        afrag[jw][ks][j] = x2buf[(OFF2 + v * d2 + (J0 + jw)) * P2 + bcol];
      }

  // G[i][jw] accumulates sum_u x1[u,i]*M_u[jw] in packed f16 (2 halves of 4 b-rows)
  f16x2 G[d1][JW][2];
#pragma unroll
  for (int i = 0; i < d1; ++i)
#pragma unroll
    for (int jw = 0; jw < JW; ++jw) {
      G[i][jw][0] = f16x2{(f16)0.f, (f16)0.f};
      G[i][jw][1] = f16x2{(f16)0.f, (f16)0.f};
    }

  const f16* wb = wsf + (((size_t)(PORIG * 4 + nt)) * 128 + (size_t)uq * 16) * 512 + (size_t)lane * 8;
  auto bfld = [&](int u, int ks) -> f16x8 {
    return *(const f16x8*)(wb + (size_t)(u * 2 + ks) * 512);
  };

  auto stepu = [&](int uu, f16x8 bf0, f16x8 bf1) {
    f32x4 M[JW];
#pragma unroll
    for (int jw = 0; jw < JW; ++jw) {
      f32x4 z{0.f, 0.f, 0.f, 0.f};
      M[jw] = mfma16(afrag[jw][0], bf0, z);
    }
#pragma unroll
    for (int jw = 0; jw < JW; ++jw)
      M[jw] = mfma16(afrag[jw][1], bf1, M[jw]);
    f16x2 Ml[JW], Mh[JW];
#pragma unroll
    for (int jw = 0; jw < JW; ++jw) {
      Ml[jw] = pkrtz(M[jw][0], M[jw][1]);
      Mh[jw] = pkrtz(M[jw][2], M[jw][3]);
    }
#pragma unroll
    for (int i = 0; i < d1; ++i) {
      const f16* xp = &x1buf[(OFF1 + (uq * 8 + uu) * d1 + i) * P1 + brow * 4];
      f16x2 xl = *(const f16x2*)xp;
      f16x2 xh = *(const f16x2*)(xp + 2);
#pragma unroll
      for (int jw = 0; jw < JW; ++jw)
        if (pair_used(L1, L2, L3, i, J0 + jw)) {
          G[i][jw][0] += xl * Ml[jw];
          G[i][jw][1] += xh * Mh[jw];
        }
    }
  };

  f16x8 a0 = bfld(0, 0), a1 = bfld(0, 1);
  f16x8 c0 = bfld(1, 0), c1 = bfld(1, 1);
#pragma unroll 1
  for (int up = 0; up < 4; ++up) {
    stepu(2 * up, a0, a1);
    int ua = (up < 3) ? 2 * up + 2 : 0;
    a0 = bfld(ua, 0); a1 = bfld(ua, 1);
    stepu(2 * up + 1, c0, c1);
    int ub = (up < 3) ? 2 * up + 3 : 1;
    c0 = bfld(ub, 0); c1 = bfld(ub, 1);
  }

  // C-mix once per chunk: o[k3] += C[i,jj,k3] * G[i][jj]
#pragma unroll
  for (int i = 0; i < d1; ++i)
#pragma unroll
    for (int jw = 0; jw < JW; ++jw)
      if (pair_used(L1, L2, L3, i, J0 + jw)) {
        float g0 = (float)G[i][jw][0][0], g1 = (float)G[i][jw][0][1];
        float g2 = (float)G[i][jw][1][0], g3 = (float)G[i][jw][1][1];
#pragma unroll
        for (int k3 = 0; k3 < d3; ++k3)
          if (w3j_nz(L1, L2, L3, i, J0 + jw, k3)) {
            float cv = kc.c[COFF + (i * d2 + (J0 + jw)) * d3 + k3];
            o[k3][0] = fmaf(cv, g0, o[k3][0]);
            o[k3][1] = fmaf(cv, g1, o[k3][1]);
            o[k3][2] = fmaf(cv, g2, o[k3][2]);
            o[k3][3] = fmaf(cv, g3, o[k3][3]);
          }
      }
}

template <int L1, int L2, int L3, int PORIG, int COFF>
__device__ __forceinline__ void process_path(
    const f16* __restrict__ x2buf, const f16* __restrict__ x1buf,
    const f16* __restrict__ wsf, const KC& kc,
    int lane, int nt, int uq, f32x4 (&o)[5]) {
  constexpr int d2 = 2 * L2 + 1;
  if constexpr (d2 == 1) {
    run_chunk<L1, L2, L3, PORIG, COFF, 0, 1>(x2buf, x1buf, wsf, kc, lane, nt, uq, o);
  } else if constexpr (d2 == 3) {
    run_chunk<L1, L2, L3, PORIG, COFF, 0, 2>(x2buf, x1buf, wsf, kc, lane, nt, uq, o);
    run_chunk<L1, L2, L3, PORIG, COFF, 2, 1>(x2buf, x1buf, wsf, kc, lane, nt, uq, o);
  } else {
    run_chunk<L1, L2, L3, PORIG, COFF, 0, 2>(x2buf, x1buf, wsf, kc, lane, nt, uq, o);
    run_chunk<L1, L2, L3, PORIG, COFF, 2, 2>(x2buf, x1buf, wsf, kc, lane, nt, uq, o);
    run_chunk<L1, L2, L3, PORIG, COFF, 4, 1>(x2buf, x1buf, wsf, kc, lane, nt, uq, o);
  }
}

// reduce 8 wave-partials through rbuf, one k3-plane at a time, store to global
template <int L3, int OFF3>
__device__ __forceinline__ void store_group(float* __restrict__ out, float* rbuf,
                                            int b0, int tid, int lane, int nt, int uq,
                                            f32x4 (&o)[5]) {
  constexpr int d3 = 2 * L3 + 1;
  const int brow = lane >> 4, bcol = lane & 15;
#pragma unroll 1
  for (int k3 = 0; k3 < d3; ++k3) {
    __syncthreads();  // previous plane's readers done
    *(f32x4*)&rbuf[uq * 256 + brow * 64 + bcol * 4] = o[k3];
    __syncthreads();
    if (tid < 256) {
      int row = tid >> 4, col = tid & 15;
      int base = (row >> 2) * 64 + col * 4 + (row & 3);
      float s = 0.f;
#pragma unroll
      for (int p = 0; p < 8; ++p) s += rbuf[p * 256 + base];
      out[(size_t)(b0 + row) * FEAT + OFF3 + (nt * 16 + col) * d3 + k3] = s;
    }
  }
#pragma unroll
  for (int k3 = 0; k3 < 5; ++k3) o[k3] = f32x4{0.f, 0.f, 0.f, 0.f};
}

__global__ __launch_bounds__(512, 6) void tp_main(
    const float* __restrict__ x1, const float* __restrict__ x2,
    const f16* __restrict__ wsf, float* __restrict__ out, KC kc) {
  __shared__ alignas(16) f16 x1buf[FEAT * P1];   // 20736 B
  __shared__ alignas(16) f16 x2buf[FEAT * P2];   // 19584 B
  __shared__ alignas(16) float rbuf[8 * 256];    //  8192 B

  int tid = threadIdx.x;
  int lane = tid & 63, uq = tid >> 6;  // 8 waves = 8 u-slices of 8
  int blk = blockIdx.x;                // 1024 blocks = 256 btiles x 4 nt
  int nt = blk & 3, btile = blk >> 2;
  int b0 = btile * BT;

  // ---- stage x1, x2 (all 576 feats, BT rows) once ----
#pragma unroll 1
  for (int t = tid; t < BT * 144; t += 512) {
    int b = t / 144, f4 = t - b * 144;
    f32x4 v2 = *(const f32x4*)&x2[(size_t)(b0 + b) * FEAT + 4 * f4];
    f32x4 v1 = *(const f32x4*)&x1[(size_t)(b0 + b) * FEAT + 4 * f4];
#pragma unroll
    for (int k = 0; k < 4; ++k) {
      x2buf[(4 * f4 + k) * P2 + b] = (f16)v2[k];
      x1buf[(4 * f4 + k) * P1 + b] = (f16)v1[k];
    }
  }
  __syncthreads();

  f32x4 o[5];
#pragma unroll
  for (int k = 0; k < 5; ++k) o[k] = f32x4{0.f, 0.f, 0.f, 0.f};

  // i3 = 0 group (out feats [0,64), d3=1)
  process_path<0, 0, 0, 0, 0>(x2buf, x1buf, wsf, kc, lane, nt, uq, o);
  process_path<1, 1, 0, 4, 44>(x2buf, x1buf, wsf, kc, lane, nt, uq, o);
  process_path<2, 2, 0, 9, 213>(x2buf, x1buf, wsf, kc, lane, nt, uq, o);
  store_group<0, 0>(out, rbuf, b0, tid, lane, nt, uq, o);
  // i3 = 1 group (out feats [64,256), d3=3)
  process_path<0, 1, 1, 1, 1>(x2buf, x1buf, wsf, kc, lane, nt, uq, o);
  process_path<1, 0, 1, 3, 35>(x2buf, x1buf, wsf, kc, lane, nt, uq, o);
  process_path<1, 2, 1, 6, 98>(x2buf, x1buf, wsf, kc, lane, nt, uq, o);
  process_path<2, 1, 1, 8, 168>(x2buf, x1buf, wsf, kc, lane, nt, uq, o);
  store_group<1, 64>(out, rbuf, b0, tid, lane, nt, uq, o);
  // i3 = 2 group (out feats [256,576), d3=5)
  process_path<0, 2, 2, 2, 10>(x2buf, x1buf, wsf, kc, lane, nt, uq, o);
  process_path<1, 1, 2, 5, 53>(x2buf, x1buf, wsf, kc, lane, nt, uq, o);
  process_path<2, 0, 2, 7, 143>(x2buf, x1buf, wsf, kc, lane, nt, uq, o);
  process_path<2, 2, 2, 10, 238>(x2buf, x1buf, wsf, kc, lane, nt, uq, o);
  store_group<2, 256>(out, rbuf, b0, tid, lane, nt, uq, o);
}

// ---------------- host: exact port of reference Wigner-3j construction ----------------
static double factd(int n) { double r = 1; for (int i = 2; i <= n; ++i) r *= i; return r; }

static double su2_cg(int j1, int j2, int j3, int m1, int m2, int m3) {
  if (m1 + m2 != m3) return 0.0;
  double pre = std::sqrt((2 * j3 + 1) * factd(j1 + j2 - j3) * factd(j1 - j2 + j3) * factd(-j1 + j2 + j3) / factd(j1 + j2 + j3 + 1));
  pre *= std::sqrt(factd(j3 + m3) * factd(j3 - m3) * factd(j1 - m1) * factd(j1 + m1) * factd(j2 - m2) * factd(j2 + m2));
  double s = 0.0;
  for (int v = 0; v <= j1 + j2 - j3; ++v) {
    int t[6] = {v, j1 + j2 - j3 - v, j1 - m1 - v, j2 + m2 - v, j3 - j2 + m1 + v, j3 - j1 - m2 + v};
    bool ok = true;
    for (int x = 0; x < 6; ++x) if (t[x] < 0) ok = false;
    if (!ok) continue;
    double den = 1.0;
    for (int x = 0; x < 6; ++x) den *= factd(t[x]);
    s += ((v & 1) ? -1.0 : 1.0) / den;
  }
  return pre * s;
}

static void qmat(int l, std::complex<double> q[5][5]) {
  int n = 2 * l + 1;
  for (int i = 0; i < 5; ++i) for (int j = 0; j < 5; ++j) q[i][j] = 0.0;
  const double s = 1.0 / std::sqrt(2.0);
  for (int m = -l; m < 0; ++m) {
    q[l + m][l - m] = s;
    q[l + m][l + m] = std::complex<double>(0.0, -s);
  }
  q[l][l] = 1.0;
  for (int m = 1; m <= l; ++m) {
    double sg = (m % 2) ? -1.0 : 1.0;
    q[l + m][l + m] = sg * s;
    q[l + m][l - m] = std::complex<double>(0.0, sg * s);
  }
  std::complex<double> pref(1.0, 0.0);
  for (int t = 0; t < l; ++t) pref *= std::complex<double>(0.0, -1.0);
  for (int i = 0; i < n; ++i) for (int j = 0; j < n; ++j) q[i][j] *= pref;
}

static void compute_w3j(int l1, int l2, int l3, float* dst) {
  int n1 = 2 * l1 + 1, n2 = 2 * l2 + 1, n3 = 2 * l3 + 1;
  std::complex<double> q1[5][5], q2[5][5], q3[5][5];
  qmat(l1, q1); qmat(l2, q2); qmat(l3, q3);
  double nrm = 0.0;
  double C[5][5][5];
  for (int a = 0; a < n1; ++a)
    for (int b = 0; b < n2; ++b)
      for (int c = 0; c < n3; ++c) {
        std::complex<double> acc(0.0, 0.0);
        for (int i = 0; i < n1; ++i)
          for (int j = 0; j < n2; ++j)
            for (int k = 0; k < n3; ++k) {
              double cg = su2_cg(l1, l2, l3, i - l1, j - l2, k - l3);
              if (cg != 0.0) acc += q1[i][a] * q2[j][b] * std::conj(q3[k][c]) * cg;
            }
        C[a][b][c] = acc.real();
        nrm += acc.real() * acc.real();
      }
  double inv = 1.0 / std::sqrt(nrm);
  for (int a = 0; a < n1; ++a)
    for (int b = 0; b < n2; ++b)
      for (int c = 0; c < n3; ++c)
        dst[(a * n2 + b) * n3 + c] = (float)(C[a][b][c] * inv);
}

extern "C" void kernel_launch(void* const* d_in, const int* in_sizes, int n_in,
                              void* d_out, int out_size, void* d_ws, size_t ws_size,
                              hipStream_t stream) {
  const float* x1 = (const float*)d_in[0];
  const float* x2 = (const float*)d_in[1];
  const float* ws = (const float*)d_in[2];
  float* out = (float*)d_out;
  f16* wsf = (f16*)d_ws;

  KC kc;
  {
    static const int L1[11] = {0, 0, 0, 1, 1, 1, 1, 2, 2, 2, 2};
    static const int L2[11] = {0, 1, 2, 0, 1, 1, 2, 0, 1, 2, 2};
    static const int L3[11] = {0, 1, 2, 1, 0, 2, 1, 2, 1, 0, 2};
    static const int COFFS[11] = {0, 1, 10, 35, 44, 53, 98, 143, 168, 213, 238};
    for (int p = 0; p < 11; ++p) compute_w3j(L1[p], L2[p], L3[p], kc.c + COFFS[p]);
  }

  hipLaunchKernelGGL(prep_ws, dim3(11 * 128), dim3(256), 0, stream, ws, wsf);
  hipLaunchKernelGGL(tp_main, dim3(1024), dim3(512), 0, stream, x1, x2, wsf, out, kc);
}

// Round 5
// 167.646 us; speedup vs baseline: 1.2167x; 1.2167x over previous
//
#include <hip/hip_runtime.h>
#include <cmath>
#include <complex>

#define FEAT 576

typedef _Float16 f16;
typedef _Float16 f16x2 __attribute__((ext_vector_type(2)));
typedef _Float16 f16x4 __attribute__((ext_vector_type(4)));
typedef _Float16 f16x8 __attribute__((ext_vector_type(8)));
typedef float f32x4 __attribute__((ext_vector_type(4)));

struct KC { float c[363]; };

__device__ __forceinline__ f16x2 pkrtz(float a, float b) {
  auto t = __builtin_amdgcn_cvt_pkrtz(a, b);
  return __builtin_bit_cast(f16x2, t);
}

// ---------------- Wigner-3j nonzero patterns (compile-time) ----------------
__host__ __device__ constexpr bool nz112(int i, int j, int k) {
  return (k == 0) ? ((i == 2 && j == 0) || (i == 0 && j == 2))
       : (k == 1) ? ((i == 0 && j == 1) || (i == 1 && j == 0))
       : (k == 2) ? (i == j)
       : (k == 3) ? ((i == 1 && j == 2) || (i == 2 && j == 1))
       :            ((i == 0 && j == 0) || (i == 2 && j == 2));
}
__host__ __device__ constexpr bool nz222(int i, int j, int k) {
  return (k == 0) ? ((i == 1 && j == 3) || (i == 3 && j == 1) || (i == 0 && j == 2) || (i == 2 && j == 0))
       : (k == 1) ? ((i == 0 && j == 3) || (i == 3 && j == 0) || (i == 1 && j == 2) || (i == 2 && j == 1) || (i == 1 && j == 4) || (i == 4 && j == 1))
       : (k == 2) ? (i == j)
       : (k == 3) ? ((i == 0 && j == 1) || (i == 1 && j == 0) || (i == 3 && j == 2) || (i == 2 && j == 3) || (i == 3 && j == 4) || (i == 4 && j == 3))
       :            ((i == 1 && j == 1) || (i == 3 && j == 3) || (i == 2 && j == 4) || (i == 4 && j == 2));
}
__host__ __device__ constexpr bool w3j_nz(int l1, int l2, int l3, int i, int j, int k) {
  return (l1 == 0) ? (j == k)
       : (l2 == 0) ? (i == k)
       : (l3 == 0) ? (i == j)
       : (l1 == 1 && l2 == 1 && l3 == 2) ? nz112(i, j, k)
       : (l1 == 1 && l2 == 2 && l3 == 1) ? nz112(i, k, j)
       : (l1 == 2 && l2 == 1 && l3 == 1) ? nz112(j, k, i)
       : nz222(i, j, k);
}
__host__ __device__ constexpr bool pair_used(int l1, int l2, int l3, int i, int j) {
  for (int k = 0; k < 2 * l3 + 1; ++k)
    if (w3j_nz(l1, l2, l3, i, j, k)) return true;
  return false;
}

// LDS geometry helpers (compile-time)
__host__ __device__ constexpr int soff2(int L) { return L == 0 ? 0 : L == 1 ? 1152 : 4608; }   // f16 units
__host__ __device__ constexpr int soff1(int L) { return L == 0 ? 0 : L == 1 ? 1056 : 5184; }   // f16 units
__host__ __device__ constexpr int ipad(int d1) { return d1 == 1 ? 4 : d1 == 3 ? 16 : 24; }     // f16 per u

// ---------------- prep: ws f32 -> f16 in MFMA B-fragment order ----------------
// wsf[((p*4 + nt)*128 + uk)*512 + lane*8 + j] = ws[p][uv = uk*32 + (lane>>4)*8 + j][w = nt*16 + (lane&15)]
__global__ void prep_ws(const float* __restrict__ ws, f16* __restrict__ wsf) {
  int blk = blockIdx.x;            // 11*128 blocks
  int p = blk >> 7, uk = blk & 127;
  int tid = threadIdx.x;           // 256
  int nt = tid >> 6, l = tid & 63;
  int w = nt * 16 + (l & 15);
  int uvb = uk * 32 + (l >> 4) * 8;
  f16x8 v;
#pragma unroll
  for (int j = 0; j < 8; ++j)
    v[j] = (f16)ws[(size_t)p * 262144 + (size_t)(uvb + j) * 64 + w];
  *(f16x8*)(wsf + ((size_t)((p * 4 + nt) * 128 + uk)) * 512 + (size_t)l * 8) = v;
}

// ---------------- main kernel ----------------
__device__ __forceinline__ f32x4 mfma16(f16x8 a, f16x8 b, f32x4 c) {
  return __builtin_amdgcn_mfma_f32_16x16x32_f16(a, b, c, 0, 0, 0);
}

// One jj-window pass over this wave's 8 u's, both K-halves; wsf streamed once.
template <int L1, int L2, int L3, int PORIG, int COFF, int J0, int JW>
__device__ __forceinline__ void run_pass(
    const f16* __restrict__ x2t, const f16* __restrict__ x1t,
    const f16* __restrict__ wsf, const KC& kc,
    int lane, int nt, int uq, f32x4 (&o)[5]) {
  constexpr int d1 = 2 * L1 + 1, d2 = 2 * L2 + 1, d3 = 2 * L3 + 1;
  constexpr int IP = ipad(d1);
  const int brow = lane >> 4, bcol = lane & 15;

  // A fragments (x2), both ks, window jj's — ds_read_b128 each
  f16x8 af[2][JW];
#pragma unroll
  for (int ks = 0; ks < 2; ++ks)
#pragma unroll
    for (int jw = 0; jw < JW; ++jw)
      af[ks][jw] = *(const f16x8*)&x2t[soff2(L2) + ((J0 + jw) * 16 + bcol) * 72 + ks * 32 + brow * 8];

  f16x2 G[d1][JW][2];
#pragma unroll
  for (int i = 0; i < d1; ++i)
#pragma unroll
    for (int jw = 0; jw < JW; ++jw) {
      G[i][jw][0] = f16x2{(f16)0.f, (f16)0.f};
      G[i][jw][1] = f16x2{(f16)0.f, (f16)0.f};
    }

  const f16* wb = wsf + ((size_t)(PORIG * 4 + nt) * 128 + (size_t)uq * 16) * 512 + (size_t)lane * 8;
  const f16* xb = x1t + soff1(L1) + brow * (64 * IP + 8) + uq * 8 * IP;

  f16x8 bf0 = *(const f16x8*)(wb);
  f16x8 bf1 = *(const f16x8*)(wb + 512);

#pragma unroll 1
  for (int u = 0; u < 8; ++u) {
    f16x8 nbf0 = bf0, nbf1 = bf1;
    if (u < 7) {
      nbf0 = *(const f16x8*)(wb + (size_t)(u + 1) * 1024);
      nbf1 = *(const f16x8*)(wb + (size_t)(u + 1) * 1024 + 512);
    }
    // x1 for this u: i-major, 4 b's each, from padded LDS (vector reads, bcol-broadcast)
    f16x2 xl[d1], xh[d1];
    const f16* xp = xb + u * IP;
    if constexpr (d1 == 1) {
      f16x4 a = *(const f16x4*)xp;
      xl[0] = f16x2{a[0], a[1]}; xh[0] = f16x2{a[2], a[3]};
    } else if constexpr (d1 == 3) {
      f16x8 a = *(const f16x8*)xp;
      f16x4 b = *(const f16x4*)(xp + 8);
      xl[0] = f16x2{a[0], a[1]}; xh[0] = f16x2{a[2], a[3]};
      xl[1] = f16x2{a[4], a[5]}; xh[1] = f16x2{a[6], a[7]};
      xl[2] = f16x2{b[0], b[1]}; xh[2] = f16x2{b[2], b[3]};
    } else {
      f16x8 a = *(const f16x8*)xp;
      f16x8 b = *(const f16x8*)(xp + 8);
      f16x4 c = *(const f16x4*)(xp + 16);
      xl[0] = f16x2{a[0], a[1]}; xh[0] = f16x2{a[2], a[3]};
      xl[1] = f16x2{a[4], a[5]}; xh[1] = f16x2{a[6], a[7]};
      xl[2] = f16x2{b[0], b[1]}; xh[2] = f16x2{b[2], b[3]};
      xl[3] = f16x2{b[4], b[5]}; xh[3] = f16x2{b[6], b[7]};
      xl[4] = f16x2{c[0], c[1]}; xh[4] = f16x2{c[2], c[3]};
    }
#pragma unroll
    for (int ks = 0; ks < 2; ++ks) {
      f16x8 bf = ks ? bf1 : bf0;
#pragma unroll
      for (int jw = 0; jw < JW; ++jw) {
        f32x4 z{0.f, 0.f, 0.f, 0.f};
        f32x4 M = mfma16(af[ks][jw], bf, z);
        f16x2 Ml = pkrtz(M[0], M[1]);
        f16x2 Mh = pkrtz(M[2], M[3]);
#pragma unroll
        for (int i = 0; i < d1; ++i)
          if (pair_used(L1, L2, L3, i, J0 + jw)) {
            G[i][jw][0] += xl[i] * Ml;
            G[i][jw][1] += xh[i] * Mh;
          }
      }
    }
    bf0 = nbf0; bf1 = nbf1;
  }

  // C-mix once per pass: o[k3] += C[i,jj,k3] * G[i][jj]
#pragma unroll
  for (int i = 0; i < d1; ++i)
#pragma unroll
    for (int jw = 0; jw < JW; ++jw)
      if (pair_used(L1, L2, L3, i, J0 + jw)) {
        float g0 = (float)G[i][jw][0][0], g1 = (float)G[i][jw][0][1];
        float g2 = (float)G[i][jw][1][0], g3 = (float)G[i][jw][1][1];
#pragma unroll
        for (int k3 = 0; k3 < d3; ++k3)
          if (w3j_nz(L1, L2, L3, i, J0 + jw, k3)) {
            float cv = kc.c[COFF + (i * d2 + (J0 + jw)) * d3 + k3];
            o[k3][0] = fmaf(cv, g0, o[k3][0]);
            o[k3][1] = fmaf(cv, g1, o[k3][1]);
            o[k3][2] = fmaf(cv, g2, o[k3][2]);
            o[k3][3] = fmaf(cv, g3, o[k3][3]);
          }
      }
}

// reduce 8 wave-partials (4 slots + RMW) and store contiguous full lines
template <int L3, int OFF3>
__device__ __forceinline__ void store_group(float* __restrict__ out, float* rbuf,
                                            int b0, int tid, int lane, int nt, int uq,
                                            f32x4 (&o)[5]) {
  constexpr int d3 = 2 * L3 + 1;
  constexpr int RS = 16 * d3 + 4;   // row stride (floats), 16B-aligned, bank-spread
  constexpr int SS = 16 * RS;       // slot stride
  const int brow = lane >> 4, bcol = lane & 15;
  __syncthreads();                  // previous reduce done; o final
  if (uq < 4) {
    float* s = rbuf + uq * SS;
#pragma unroll
    for (int k3 = 0; k3 < d3; ++k3)
#pragma unroll
      for (int r = 0; r < 4; ++r)
        s[(brow * 4 + r) * RS + bcol * d3 + k3] = o[k3][r];
  }
  __syncthreads();
  if (uq >= 4) {
    float* s = rbuf + (uq - 4) * SS;
#pragma unroll
    for (int k3 = 0; k3 < d3; ++k3)
#pragma unroll
      for (int r = 0; r < 4; ++r)
        s[(brow * 4 + r) * RS + bcol * d3 + k3] += o[k3][r];
  }
  __syncthreads();
  constexpr int NT = 64 * d3;       // 16 rows × 4*d3 f32x4 chunks
  if (tid < NT) {
    int row = tid / (4 * d3);
    int c = tid - row * (4 * d3);
    f32x4 acc = *(const f32x4*)&rbuf[row * RS + c * 4];
#pragma unroll
    for (int sl = 1; sl < 4; ++sl)
      acc += *(const f32x4*)&rbuf[sl * SS + row * RS + c * 4];
    *(f32x4*)&out[(size_t)(b0 + row) * FEAT + OFF3 + nt * 16 * d3 + c * 4] = acc;
  }
#pragma unroll
  for (int k3 = 0; k3 < 5; ++k3) o[k3] = f32x4{0.f, 0.f, 0.f, 0.f};
}

__global__ __launch_bounds__(512, 4) void tp_main(
    const float* __restrict__ x1, const float* __restrict__ x2,
    const f16* __restrict__ wsf, float* __restrict__ out, KC kc) {
  __shared__ alignas(16) f16 x2t[10368];   // [jj-plane][b][v], 72-padded rows
  __shared__ alignas(16) f16 x1t[11360];   // [b4][u][i][4b], 8-padded sections
  __shared__ alignas(16) float rbuf[4 * 16 * 84];  // 21504 B (sized for d3=5)

  int tid = threadIdx.x;
  int lane = tid & 63, uq = tid >> 6;      // 8 waves = 8 u-slices of 8
  int blk = blockIdx.x;                    // 1024 blocks
  int xcd = blk & 7;                       // XCD pin: same nt per XCD-pair
  int nt = xcd >> 1;
  int btile = ((blk >> 3) << 1) | (xcd & 1);
  int b0 = btile * 16;

  // ---- stage x1, x2 (all 576 feats, 16 rows) once, transposed/padded ----
#pragma unroll 1
  for (int t = tid; t < 16 * 144; t += 512) {
    int b = t / 144, c = t - b * 144;
    f32x4 v1 = *(const f32x4*)&x1[(size_t)(b0 + b) * FEAT + 4 * c];
    f32x4 v2 = *(const f32x4*)&x2[(size_t)(b0 + b) * FEAT + 4 * c];
#pragma unroll
    for (int k = 0; k < 4; ++k) {
      int f = 4 * c + k;
      f16 e1 = (f16)v1[k], e2 = (f16)v2[k];
      if (f < 64) {
        int m = f;
        x2t[soff2(0) + b * 72 + m] = e2;
        x1t[soff1(0) + (b >> 2) * (64 * 4 + 8) + m * 4 + (b & 3)] = e1;
      } else if (f < 256) {
        int lf = f - 64, m = lf / 3, ii = lf - m * 3;
        x2t[soff2(1) + (ii * 16 + b) * 72 + m] = e2;
        x1t[soff1(1) + (b >> 2) * (64 * 16 + 8) + m * 16 + ii * 4 + (b & 3)] = e1;
      } else {
        int lf = f - 256, m = lf / 5, ii = lf - m * 5;
        x2t[soff2(2) + (ii * 16 + b) * 72 + m] = e2;
        x1t[soff1(2) + (b >> 2) * (64 * 24 + 8) + m * 24 + ii * 4 + (b & 3)] = e1;
      }
    }
  }
  __syncthreads();

  f32x4 o[5];
#pragma unroll
  for (int k = 0; k < 5; ++k) o[k] = f32x4{0.f, 0.f, 0.f, 0.f};

  // i3 = 0 group (out feats [0,64), d3=1)
  run_pass<0, 0, 0, 0, 0, 0, 1>(x2t, x1t, wsf, kc, lane, nt, uq, o);
  run_pass<1, 1, 0, 4, 44, 0, 3>(x2t, x1t, wsf, kc, lane, nt, uq, o);
  run_pass<2, 2, 0, 9, 213, 0, 3>(x2t, x1t, wsf, kc, lane, nt, uq, o);
  run_pass<2, 2, 0, 9, 213, 3, 2>(x2t, x1t, wsf, kc, lane, nt, uq, o);
  store_group<0, 0>(out, rbuf, b0, tid, lane, nt, uq, o);
  // i3 = 1 group (out feats [64,256), d3=3)
  run_pass<0, 1, 1, 1, 1, 0, 3>(x2t, x1t, wsf, kc, lane, nt, uq, o);
  run_pass<1, 0, 1, 3, 35, 0, 1>(x2t, x1t, wsf, kc, lane, nt, uq, o);
  run_pass<1, 2, 1, 6, 98, 0, 3>(x2t, x1t, wsf, kc, lane, nt, uq, o);
  run_pass<1, 2, 1, 6, 98, 3, 2>(x2t, x1t, wsf, kc, lane, nt, uq, o);
  run_pass<2, 1, 1, 8, 168, 0, 3>(x2t, x1t, wsf, kc, lane, nt, uq, o);
  store_group<1, 64>(out, rbuf, b0, tid, lane, nt, uq, o);
  // i3 = 2 group (out feats [256,576), d3=5)
  run_pass<0, 2, 2, 2, 10, 0, 5>(x2t, x1t, wsf, kc, lane, nt, uq, o);
  run_pass<1, 1, 2, 5, 53, 0, 3>(x2t, x1t, wsf, kc, lane, nt, uq, o);
  run_pass<2, 0, 2, 7, 143, 0, 1>(x2t, x1t, wsf, kc, lane, nt, uq, o);
  run_pass<2, 2, 2, 10, 238, 0, 3>(x2t, x1t, wsf, kc, lane, nt, uq, o);
  run_pass<2, 2, 2, 10, 238, 3, 2>(x2t, x1t, wsf, kc, lane, nt, uq, o);
  store_group<2, 256>(out, rbuf, b0, tid, lane, nt, uq, o);
}

// ---------------- host: exact port of reference Wigner-3j construction ----------------
static double factd(int n) { double r = 1; for (int i = 2; i <= n; ++i) r *= i; return r; }

static double su2_cg(int j1, int j2, int j3, int m1, int m2, int m3) {
  if (m1 + m2 != m3) return 0.0;
  double pre = std::sqrt((2 * j3 + 1) * factd(j1 + j2 - j3) * factd(j1 - j2 + j3) * factd(-j1 + j2 + j3) / factd(j1 + j2 + j3 + 1));
  pre *= std::sqrt(factd(j3 + m3) * factd(j3 - m3) * factd(j1 - m1) * factd(j1 + m1) * factd(j2 - m2) * factd(j2 + m2));
  double s = 0.0;
  for (int v = 0; v <= j1 + j2 - j3; ++v) {
    int t[6] = {v, j1 + j2 - j3 - v, j1 - m1 - v, j2 + m2 - v, j3 - j2 + m1 + v, j3 - j1 - m2 + v};
    bool ok = true;
    for (int x = 0; x < 6; ++x) if (t[x] < 0) ok = false;
    if (!ok) continue;
    double den = 1.0;
    for (int x = 0; x < 6; ++x) den *= factd(t[x]);
    s += ((v & 1) ? -1.0 : 1.0) / den;
  }
  return pre * s;
}

static void qmat(int l, std::complex<double> q[5][5]) {
  int n = 2 * l + 1;
  for (int i = 0; i < 5; ++i) for (int j = 0; j < 5; ++j) q[i][j] = 0.0;
  const double s = 1.0 / std::sqrt(2.0);
  for (int m = -l; m < 0; ++m) {
    q[l + m][l - m] = s;
    q[l + m][l + m] = std::complex<double>(0.0, -s);
  }
  q[l][l] = 1.0;
  for (int m = 1; m <= l; ++m) {
    double sg = (m % 2) ? -1.0 : 1.0;
    q[l + m][l + m] = sg * s;
    q[l + m][l - m] = std::complex<double>(0.0, sg * s);
  }
  std::complex<double> pref(1.0, 0.0);
  for (int t = 0; t < l; ++t) pref *= std::complex<double>(0.0, -1.0);
  for (int i = 0; i < n; ++i) for (int j = 0; j < n; ++j) q[i][j] *= pref;
}

static void compute_w3j(int l1, int l2, int l3, float* dst) {
  int n1 = 2 * l1 + 1, n2 = 2 * l2 + 1, n3 = 2 * l3 + 1;
  std::complex<double> q1[5][5], q2[5][5], q3[5][5];
  qmat(l1, q1); qmat(l2, q2); qmat(l3, q3);
  double nrm = 0.0;
  double C[5][5][5];
  for (int a = 0; a < n1; ++a)
    for (int b = 0; b < n2; ++b)
      for (int c = 0; c < n3; ++c) {
        std::complex<double> acc(0.0, 0.0);
        for (int i = 0; i < n1; ++i)
          for (int j = 0; j < n2; ++j)
            for (int k = 0; k < n3; ++k) {
              double cg = su2_cg(l1, l2, l3, i - l1, j - l2, k - l3);
              if (cg != 0.0) acc += q1[i][a] * q2[j][b] * std::conj(q3[k][c]) * cg;
            }
        C[a][b][c] = acc.real();
        nrm += acc.real() * acc.real();
      }
  double inv = 1.0 / std::sqrt(nrm);
  for (int a = 0; a < n1; ++a)
    for (int b = 0; b < n2; ++b)
      for (int c = 0; c < n3; ++c)
        dst[(a * n2 + b) * n3 + c] = (float)(C[a][b][c] * inv);
}

extern "C" void kernel_launch(void* const* d_in, const int* in_sizes, int n_in,
                              void* d_out, int out_size, void* d_ws, size_t ws_size,
                              hipStream_t stream) {
  const float* x1 = (const float*)d_in[0];
  const float* x2 = (const float*)d_in[1];
  const float* ws = (const float*)d_in[2];
  float* out = (float*)d_out;
  f16* wsf = (f16*)d_ws;

  KC kc;
  {
    static const int L1[11] = {0, 0, 0, 1, 1, 1, 1, 2, 2, 2, 2};
    static const int L2[11] = {0, 1, 2, 0, 1, 1, 2, 0, 1, 2, 2};
    static const int L3[11] = {0, 1, 2, 1, 0, 2, 1, 2, 1, 0, 2};
    static const int COFFS[11] = {0, 1, 10, 35, 44, 53, 98, 143, 168, 213, 238};
    for (int p = 0; p < 11; ++p) compute_w3j(L1[p], L2[p], L3[p], kc.c + COFFS[p]);
  }

  hipLaunchKernelGGL(prep_ws, dim3(11 * 128), dim3(256), 0, stream, ws, wsf);
  hipLaunchKernelGGL(tp_main, dim3(1024), dim3(512), 0, stream, x1, x2, wsf, out, kc);
}

// Round 6
// 167.436 us; speedup vs baseline: 1.2182x; 1.0013x over previous
//
#include <hip/hip_runtime.h>
#include <cmath>
#include <complex>

#define FEAT 576

typedef _Float16 f16;
typedef _Float16 f16x2 __attribute__((ext_vector_type(2)));
typedef _Float16 f16x4 __attribute__((ext_vector_type(4)));
typedef _Float16 f16x8 __attribute__((ext_vector_type(8)));
typedef float f32x4 __attribute__((ext_vector_type(4)));

struct KC { float c[363]; };

__device__ __forceinline__ f16x2 pkrtz(float a, float b) {
  auto t = __builtin_amdgcn_cvt_pkrtz(a, b);
  return __builtin_bit_cast(f16x2, t);
}

// ---------------- Wigner-3j nonzero patterns (compile-time) ----------------
__host__ __device__ constexpr bool nz112(int i, int j, int k) {
  return (k == 0) ? ((i == 2 && j == 0) || (i == 0 && j == 2))
       : (k == 1) ? ((i == 0 && j == 1) || (i == 1 && j == 0))
       : (k == 2) ? (i == j)
       : (k == 3) ? ((i == 1 && j == 2) || (i == 2 && j == 1))
       :            ((i == 0 && j == 0) || (i == 2 && j == 2));
}
__host__ __device__ constexpr bool nz222(int i, int j, int k) {
  return (k == 0) ? ((i == 1 && j == 3) || (i == 3 && j == 1) || (i == 0 && j == 2) || (i == 2 && j == 0))
       : (k == 1) ? ((i == 0 && j == 3) || (i == 3 && j == 0) || (i == 1 && j == 2) || (i == 2 && j == 1) || (i == 1 && j == 4) || (i == 4 && j == 1))
       : (k == 2) ? (i == j)
       : (k == 3) ? ((i == 0 && j == 1) || (i == 1 && j == 0) || (i == 3 && j == 2) || (i == 2 && j == 3) || (i == 3 && j == 4) || (i == 4 && j == 3))
       :            ((i == 1 && j == 1) || (i == 3 && j == 3) || (i == 2 && j == 4) || (i == 4 && j == 2));
}
__host__ __device__ constexpr bool w3j_nz(int l1, int l2, int l3, int i, int j, int k) {
  return (l1 == 0) ? (j == k)
       : (l2 == 0) ? (i == k)
       : (l3 == 0) ? (i == j)
       : (l1 == 1 && l2 == 1 && l3 == 2) ? nz112(i, j, k)
       : (l1 == 1 && l2 == 2 && l3 == 1) ? nz112(i, k, j)
       : (l1 == 2 && l2 == 1 && l3 == 1) ? nz112(j, k, i)
       : nz222(i, j, k);
}
__host__ __device__ constexpr bool pair_used(int l1, int l2, int l3, int i, int j) {
  for (int k = 0; k < 2 * l3 + 1; ++k)
    if (w3j_nz(l1, l2, l3, i, j, k)) return true;
  return false;
}

// LDS geometry helpers (compile-time)
__host__ __device__ constexpr int soff2(int L) { return L == 0 ? 0 : L == 1 ? 1152 : 4608; }   // f16 units
__host__ __device__ constexpr int soff1(int L) { return L == 0 ? 0 : L == 1 ? 1056 : 5184; }   // f16 units
__host__ __device__ constexpr int ipad(int d1) { return d1 == 1 ? 4 : d1 == 3 ? 16 : 24; }     // f16 per u

// ---------------- prep: ws f32 -> f16 in MFMA B-fragment order ----------------
// wsf[((p*4 + nt)*128 + uk)*512 + lane*8 + j] = ws[p][uv = uk*32 + (lane>>4)*8 + j][w = nt*16 + (lane&15)]
__global__ void prep_ws(const float* __restrict__ ws, f16* __restrict__ wsf) {
  int blk = blockIdx.x;            // 11*128 blocks
  int p = blk >> 7, uk = blk & 127;
  int tid = threadIdx.x;           // 256
  int nt = tid >> 6, l = tid & 63;
  int w = nt * 16 + (l & 15);
  int uvb = uk * 32 + (l >> 4) * 8;
  f16x8 v;
#pragma unroll
  for (int j = 0; j < 8; ++j)
    v[j] = (f16)ws[(size_t)p * 262144 + (size_t)(uvb + j) * 64 + w];
  *(f16x8*)(wsf + ((size_t)((p * 4 + nt) * 128 + uk)) * 512 + (size_t)l * 8) = v;
}

// ---------------- main kernel ----------------
__device__ __forceinline__ f32x4 mfma16(f16x8 a, f16x8 b, f32x4 c) {
  return __builtin_amdgcn_mfma_f32_16x16x32_f16(a, b, c, 0, 0, 0);
}

// One jj-window pass over this wave's 8 u's, both K-halves; wsf streamed once.
template <int L1, int L2, int L3, int PORIG, int COFF, int J0, int JW>
__device__ __forceinline__ void run_pass(
    const f16* __restrict__ x2t, const f16* __restrict__ x1t,
    const f16* __restrict__ wsf, const KC& kc,
    int lane, int nt, int uq, f32x4 (&o)[5]) {
  constexpr int d1 = 2 * L1 + 1, d2 = 2 * L2 + 1, d3 = 2 * L3 + 1;
  constexpr int IP = ipad(d1);
  const int brow = lane >> 4, bcol = lane & 15;

  // A fragments (x2), both ks, window jj's — ds_read_b128 each
  f16x8 af[2][JW];
#pragma unroll
  for (int ks = 0; ks < 2; ++ks)
#pragma unroll
    for (int jw = 0; jw < JW; ++jw)
      af[ks][jw] = *(const f16x8*)&x2t[soff2(L2) + ((J0 + jw) * 16 + bcol) * 72 + ks * 32 + brow * 8];

  f16x2 G[d1][JW][2];
#pragma unroll
  for (int i = 0; i < d1; ++i)
#pragma unroll
    for (int jw = 0; jw < JW; ++jw) {
      G[i][jw][0] = f16x2{(f16)0.f, (f16)0.f};
      G[i][jw][1] = f16x2{(f16)0.f, (f16)0.f};
    }

  const f16* wb = wsf + ((size_t)(PORIG * 4 + nt) * 128 + (size_t)uq * 16) * 512 + (size_t)lane * 8;
  const f16* xb = x1t + soff1(L1) + brow * (64 * IP + 8) + uq * 8 * IP;

  f16x8 bf0 = *(const f16x8*)(wb);
  f16x8 bf1 = *(const f16x8*)(wb + 512);

#pragma unroll 1
  for (int u = 0; u < 8; ++u) {
    f16x8 nbf0 = bf0, nbf1 = bf1;
    if (u < 7) {
      nbf0 = *(const f16x8*)(wb + (size_t)(u + 1) * 1024);
      nbf1 = *(const f16x8*)(wb + (size_t)(u + 1) * 1024 + 512);
    }
    // x1 for this u: i-major, 4 b's each, from padded LDS (vector reads, bcol-broadcast)
    f16x2 xl[d1], xh[d1];
    const f16* xp = xb + u * IP;
    if constexpr (d1 == 1) {
      f16x4 a = *(const f16x4*)xp;
      xl[0] = f16x2{a[0], a[1]}; xh[0] = f16x2{a[2], a[3]};
    } else if constexpr (d1 == 3) {
      f16x8 a = *(const f16x8*)xp;
      f16x4 b = *(const f16x4*)(xp + 8);
      xl[0] = f16x2{a[0], a[1]}; xh[0] = f16x2{a[2], a[3]};
      xl[1] = f16x2{a[4], a[5]}; xh[1] = f16x2{a[6], a[7]};
      xl[2] = f16x2{b[0], b[1]}; xh[2] = f16x2{b[2], b[3]};
    } else {
      f16x8 a = *(const f16x8*)xp;
      f16x8 b = *(const f16x8*)(xp + 8);
      f16x4 c = *(const f16x4*)(xp + 16);
      xl[0] = f16x2{a[0], a[1]}; xh[0] = f16x2{a[2], a[3]};
      xl[1] = f16x2{a[4], a[5]}; xh[1] = f16x2{a[6], a[7]};
      xl[2] = f16x2{b[0], b[1]}; xh[2] = f16x2{b[2], b[3]};
      xl[3] = f16x2{b[4], b[5]}; xh[3] = f16x2{b[6], b[7]};
      xl[4] = f16x2{c[0], c[1]}; xh[4] = f16x2{c[2], c[3]};
    }
#pragma unroll
    for (int ks = 0; ks < 2; ++ks) {
      f16x8 bf = ks ? bf1 : bf0;
#pragma unroll
      for (int jw = 0; jw < JW; ++jw) {
        f32x4 z{0.f, 0.f, 0.f, 0.f};
        f32x4 M = mfma16(af[ks][jw], bf, z);
        f16x2 Ml = pkrtz(M[0], M[1]);
        f16x2 Mh = pkrtz(M[2], M[3]);
#pragma unroll
        for (int i = 0; i < d1; ++i)
          if (pair_used(L1, L2, L3, i, J0 + jw)) {
            G[i][jw][0] += xl[i] * Ml;
            G[i][jw][1] += xh[i] * Mh;
          }
      }
    }
    bf0 = nbf0; bf1 = nbf1;
  }

  // C-mix once per pass: o[k3] += C[i,jj,k3] * G[i][jj]
#pragma unroll
  for (int i = 0; i < d1; ++i)
#pragma unroll
    for (int jw = 0; jw < JW; ++jw)
      if (pair_used(L1, L2, L3, i, J0 + jw)) {
        float g0 = (float)G[i][jw][0][0], g1 = (float)G[i][jw][0][1];
        float g2 = (float)G[i][jw][1][0], g3 = (float)G[i][jw][1][1];
#pragma unroll
        for (int k3 = 0; k3 < d3; ++k3)
          if (w3j_nz(L1, L2, L3, i, J0 + jw, k3)) {
            float cv = kc.c[COFF + (i * d2 + (J0 + jw)) * d3 + k3];
            o[k3][0] = fmaf(cv, g0, o[k3][0]);
            o[k3][1] = fmaf(cv, g1, o[k3][1]);
            o[k3][2] = fmaf(cv, g2, o[k3][2]);
            o[k3][3] = fmaf(cv, g3, o[k3][3]);
          }
      }
}

// reduce 8 wave-partials (4 slots + RMW) and store contiguous full lines
template <int L3, int OFF3>
__device__ __forceinline__ void store_group(float* __restrict__ out, float* rbuf,
                                            int b0, int tid, int lane, int nt, int uq,
                                            f32x4 (&o)[5]) {
  constexpr int d3 = 2 * L3 + 1;
  constexpr int RS = 16 * d3 + 4;   // row stride (floats), 16B-aligned, bank-spread
  constexpr int SS = 16 * RS;       // slot stride
  const int brow = lane >> 4, bcol = lane & 15;
  __syncthreads();                  // previous reduce done; o final
  if (uq < 4) {
    float* s = rbuf + uq * SS;
#pragma unroll
    for (int k3 = 0; k3 < d3; ++k3)
#pragma unroll
      for (int r = 0; r < 4; ++r)
        s[(brow * 4 + r) * RS + bcol * d3 + k3] = o[k3][r];
  }
  __syncthreads();
  if (uq >= 4) {
    float* s = rbuf + (uq - 4) * SS;
#pragma unroll
    for (int k3 = 0; k3 < d3; ++k3)
#pragma unroll
      for (int r = 0; r < 4; ++r)
        s[(brow * 4 + r) * RS + bcol * d3 + k3] += o[k3][r];
  }
  __syncthreads();
  constexpr int NT = 64 * d3;       // 16 rows × 4*d3 f32x4 chunks
  if (tid < NT) {
    int row = tid / (4 * d3);
    int c = tid - row * (4 * d3);
    f32x4 acc = *(const f32x4*)&rbuf[row * RS + c * 4];
#pragma unroll
    for (int sl = 1; sl < 4; ++sl)
      acc += *(const f32x4*)&rbuf[sl * SS + row * RS + c * 4];
    *(f32x4*)&out[(size_t)(b0 + row) * FEAT + OFF3 + nt * 16 * d3 + c * 4] = acc;
  }
#pragma unroll
  for (int k3 = 0; k3 < 5; ++k3) o[k3] = f32x4{0.f, 0.f, 0.f, 0.f};
}

__global__ __launch_bounds__(512, 4) void tp_main(
    const float* __restrict__ x1, const float* __restrict__ x2,
    const f16* __restrict__ wsf, float* __restrict__ out, KC kc) {
  __shared__ alignas(16) f16 x2t[10368];   // [jj-plane][b][v], 72-padded rows
  __shared__ alignas(16) f16 x1t[11360];   // [b4][u][i][4b], 8-padded sections
  __shared__ alignas(16) float rbuf[4 * 16 * 84];  // 21504 B (sized for d3=5)

  int tid = threadIdx.x;
  int lane = tid & 63, uq = tid >> 6;      // 8 waves = 8 u-slices of 8
  int blk = blockIdx.x;                    // 1024 blocks
  int xcd = blk & 7;                       // XCD pin: same nt per XCD-pair
  int nt = xcd >> 1;
  int btile = ((blk >> 3) << 1) | (xcd & 1);
  int b0 = btile * 16;

  // ---- stage x1, x2 (all 576 feats, 16 rows) once, transposed/padded ----
#pragma unroll 1
  for (int t = tid; t < 16 * 144; t += 512) {
    int b = t / 144, c = t - b * 144;
    f32x4 v1 = *(const f32x4*)&x1[(size_t)(b0 + b) * FEAT + 4 * c];
    f32x4 v2 = *(const f32x4*)&x2[(size_t)(b0 + b) * FEAT + 4 * c];
#pragma unroll
    for (int k = 0; k < 4; ++k) {
      int f = 4 * c + k;
      f16 e1 = (f16)v1[k], e2 = (f16)v2[k];
      if (f < 64) {
        int m = f;
        x2t[soff2(0) + b * 72 + m] = e2;
        x1t[soff1(0) + (b >> 2) * (64 * 4 + 8) + m * 4 + (b & 3)] = e1;
      } else if (f < 256) {
        int lf = f - 64, m = lf / 3, ii = lf - m * 3;
        x2t[soff2(1) + (ii * 16 + b) * 72 + m] = e2;
        x1t[soff1(1) + (b >> 2) * (64 * 16 + 8) + m * 16 + ii * 4 + (b & 3)] = e1;
      } else {
        int lf = f - 256, m = lf / 5, ii = lf - m * 5;
        x2t[soff2(2) + (ii * 16 + b) * 72 + m] = e2;
        x1t[soff1(2) + (b >> 2) * (64 * 24 + 8) + m * 24 + ii * 4 + (b & 3)] = e1;
      }
    }
  }
  __syncthreads();

  f32x4 o[5];
#pragma unroll
  for (int k = 0; k < 5; ++k) o[k] = f32x4{0.f, 0.f, 0.f, 0.f};

  // i3 = 0 group (out feats [0,64), d3=1)
  run_pass<0, 0, 0, 0, 0, 0, 1>(x2t, x1t, wsf, kc, lane, nt, uq, o);
  run_pass<1, 1, 0, 4, 44, 0, 3>(x2t, x1t, wsf, kc, lane, nt, uq, o);
  run_pass<2, 2, 0, 9, 213, 0, 3>(x2t, x1t, wsf, kc, lane, nt, uq, o);
  run_pass<2, 2, 0, 9, 213, 3, 2>(x2t, x1t, wsf, kc, lane, nt, uq, o);
  store_group<0, 0>(out, rbuf, b0, tid, lane, nt, uq, o);
  // i3 = 1 group (out feats [64,256), d3=3)
  run_pass<0, 1, 1, 1, 1, 0, 3>(x2t, x1t, wsf, kc, lane, nt, uq, o);
  run_pass<1, 0, 1, 3, 35, 0, 1>(x2t, x1t, wsf, kc, lane, nt, uq, o);
  run_pass<1, 2, 1, 6, 98, 0, 3>(x2t, x1t, wsf, kc, lane, nt, uq, o);
  run_pass<1, 2, 1, 6, 98, 3, 2>(x2t, x1t, wsf, kc, lane, nt, uq, o);
  run_pass<2, 1, 1, 8, 168, 0, 3>(x2t, x1t, wsf, kc, lane, nt, uq, o);
  store_group<1, 64>(out, rbuf, b0, tid, lane, nt, uq, o);
  // i3 = 2 group (out feats [256,576), d3=5)
  run_pass<0, 2, 2, 2, 10, 0, 5>(x2t, x1t, wsf, kc, lane, nt, uq, o);
  run_pass<1, 1, 2, 5, 53, 0, 3>(x2t, x1t, wsf, kc, lane, nt, uq, o);
  run_pass<2, 0, 2, 7, 143, 0, 1>(x2t, x1t, wsf, kc, lane, nt, uq, o);
  run_pass<2, 2, 2, 10, 238, 0, 3>(x2t, x1t, wsf, kc, lane, nt, uq, o);
  run_pass<2, 2, 2, 10, 238, 3, 2>(x2t, x1t, wsf, kc, lane, nt, uq, o);
  store_group<2, 256>(out, rbuf, b0, tid, lane, nt, uq, o);
}

// ---------------- host: exact port of reference Wigner-3j construction ----------------
static double factd(int n) { double r = 1; for (int i = 2; i <= n; ++i) r *= i; return r; }

static double su2_cg(int j1, int j2, int j3, int m1, int m2, int m3) {
  if (m1 + m2 != m3) return 0.0;
  double pre = std::sqrt((2 * j3 + 1) * factd(j1 + j2 - j3) * factd(j1 - j2 + j3) * factd(-j1 + j2 + j3) / factd(j1 + j2 + j3 + 1));
  pre *= std::sqrt(factd(j3 + m3) * factd(j3 - m3) * factd(j1 - m1) * factd(j1 + m1) * factd(j2 - m2) * factd(j2 + m2));
  double s = 0.0;
  for (int v = 0; v <= j1 + j2 - j3; ++v) {
    int t[6] = {v, j1 + j2 - j3 - v, j1 - m1 - v, j2 + m2 - v, j3 - j2 + m1 + v, j3 - j1 - m2 + v};
    bool ok = true;
    for (int x = 0; x < 6; ++x) if (t[x] < 0) ok = false;
    if (!ok) continue;
    double den = 1.0;
    for (int x = 0; x < 6; ++x) den *= factd(t[x]);
    s += ((v & 1) ? -1.0 : 1.0) / den;
  }
  return pre * s;
}

static void qmat(int l, std::complex<double> q[5][5]) {
  int n = 2 * l + 1;
  for (int i = 0; i < 5; ++i) for (int j = 0; j < 5; ++j) q[i][j] = 0.0;
  const double s = 1.0 / std::sqrt(2.0);
  for (int m = -l; m < 0; ++m) {
    q[l + m][l - m] = s;
    q[l + m][l + m] = std::complex<double>(0.0, -s);
  }
  q[l][l] = 1.0;
  for (int m = 1; m <= l; ++m) {
    double sg = (m % 2) ? -1.0 : 1.0;
    q[l + m][l + m] = sg * s;
    q[l + m][l - m] = std::complex<double>(0.0, sg * s);
  }
  std::complex<double> pref(1.0, 0.0);
  for (int t = 0; t < l; ++t) pref *= std::complex<double>(0.0, -1.0);
  for (int i = 0; i < n; ++i) for (int j = 0; j < n; ++j) q[i][j] *= pref;
}

static void compute_w3j(int l1, int l2, int l3, float* dst) {
  int n1 = 2 * l1 + 1, n2 = 2 * l2 + 1, n3 = 2 * l3 + 1;
  std::complex<double> q1[5][5], q2[5][5], q3[5][5];
  qmat(l1, q1); qmat(l2, q2); qmat(l3, q3);
  double nrm = 0.0;
  double C[5][5][5];
  for (int a = 0; a < n1; ++a)
    for (int b = 0; b < n2; ++b)
      for (int c = 0; c < n3; ++c) {
        std::complex<double> acc(0.0, 0.0);
        for (int i = 0; i < n1; ++i)
          for (int j = 0; j < n2; ++j)
            for (int k = 0; k < n3; ++k) {
              double cg = su2_cg(l1, l2, l3, i - l1, j - l2, k - l3);
              if (cg != 0.0) acc += q1[i][a] * q2[j][b] * std::conj(q3[k][c]) * cg;
            }
        C[a][b][c] = acc.real();
        nrm += acc.real() * acc.real();
      }
  double inv = 1.0 / std::sqrt(nrm);
  for (int a = 0; a < n1; ++a)
    for (int b = 0; b < n2; ++b)
      for (int c = 0; c < n3; ++c)
        dst[(a * n2 + b) * n3 + c] = (float)(C[a][b][c] * inv);
}

extern "C" void kernel_launch(void* const* d_in, const int* in_sizes, int n_in,
                              void* d_out, int out_size, void* d_ws, size_t ws_size,
                              hipStream_t stream) {
  const float* x1 = (const float*)d_in[0];
  const float* x2 = (const float*)d_in[1];
  const float* ws = (const float*)d_in[2];
  float* out = (float*)d_out;
  f16* wsf = (f16*)d_ws;

  KC kc;
  {
    static const int L1[11] = {0, 0, 0, 1, 1, 1, 1, 2, 2, 2, 2};
    static const int L2[11] = {0, 1, 2, 0, 1, 1, 2, 0, 1, 2, 2};
    static const int L3[11] = {0, 1, 2, 1, 0, 2, 1, 2, 1, 0, 2};
    static const int COFFS[11] = {0, 1, 10, 35, 44, 53, 98, 143, 168, 213, 238};
    for (int p = 0; p < 11; ++p) compute_w3j(L1[p], L2[p], L3[p], kc.c + COFFS[p]);
  }

  hipLaunchKernelGGL(prep_ws, dim3(11 * 128), dim3(256), 0, stream, ws, wsf);
  hipLaunchKernelGGL(tp_main, dim3(1024), dim3(512), 0, stream, x1, x2, wsf, out, kc);
}

// Round 7
// 167.061 us; speedup vs baseline: 1.2209x; 1.0022x over previous
//
#include <hip/hip_runtime.h>
#include <cmath>
#include <complex>

#define FEAT 576

typedef _Float16 f16;
typedef _Float16 f16x2 __attribute__((ext_vector_type(2)));
typedef _Float16 f16x4 __attribute__((ext_vector_type(4)));
typedef _Float16 f16x8 __attribute__((ext_vector_type(8)));
typedef float f32x4 __attribute__((ext_vector_type(4)));

struct KC { float c[363]; };

__device__ __forceinline__ f16x2 pkrtz(float a, float b) {
  auto t = __builtin_amdgcn_cvt_pkrtz(a, b);
  return __builtin_bit_cast(f16x2, t);
}

// ---------------- Wigner-3j nonzero patterns (compile-time) ----------------
__host__ __device__ constexpr bool nz112(int i, int j, int k) {
  return (k == 0) ? ((i == 2 && j == 0) || (i == 0 && j == 2))
       : (k == 1) ? ((i == 0 && j == 1) || (i == 1 && j == 0))
       : (k == 2) ? (i == j)
       : (k == 3) ? ((i == 1 && j == 2) || (i == 2 && j == 1))
       :            ((i == 0 && j == 0) || (i == 2 && j == 2));
}
__host__ __device__ constexpr bool nz222(int i, int j, int k) {
  return (k == 0) ? ((i == 1 && j == 3) || (i == 3 && j == 1) || (i == 0 && j == 2) || (i == 2 && j == 0))
       : (k == 1) ? ((i == 0 && j == 3) || (i == 3 && j == 0) || (i == 1 && j == 2) || (i == 2 && j == 1) || (i == 1 && j == 4) || (i == 4 && j == 1))
       : (k == 2) ? (i == j)
       : (k == 3) ? ((i == 0 && j == 1) || (i == 1 && j == 0) || (i == 3 && j == 2) || (i == 2 && j == 3) || (i == 3 && j == 4) || (i == 4 && j == 3))
       :            ((i == 1 && j == 1) || (i == 3 && j == 3) || (i == 2 && j == 4) || (i == 4 && j == 2));
}
__host__ __device__ constexpr bool w3j_nz(int l1, int l2, int l3, int i, int j, int k) {
  return (l1 == 0) ? (j == k)
       : (l2 == 0) ? (i == k)
       : (l3 == 0) ? (i == j)
       : (l1 == 1 && l2 == 1 && l3 == 2) ? nz112(i, j, k)
       : (l1 == 1 && l2 == 2 && l3 == 1) ? nz112(i, k, j)
       : (l1 == 2 && l2 == 1 && l3 == 1) ? nz112(j, k, i)
       : nz222(i, j, k);
}
__host__ __device__ constexpr bool pair_used(int l1, int l2, int l3, int i, int j) {
  for (int k = 0; k < 2 * l3 + 1; ++k)
    if (w3j_nz(l1, l2, l3, i, j, k)) return true;
  return false;
}

// LDS geometry helpers (compile-time)
__host__ __device__ constexpr int soff2(int L) { return L == 0 ? 0 : L == 1 ? 1152 : 4608; }   // f16 units
__host__ __device__ constexpr int soff1(int L) { return L == 0 ? 0 : L == 1 ? 1056 : 5184; }   // f16 units
__host__ __device__ constexpr int ipad(int d1) { return d1 == 1 ? 4 : d1 == 3 ? 16 : 24; }     // f16 per u

// ---------------- prep: ws f32 -> f16 in MFMA B-fragment order ----------------
// wsf[((p*4 + nt)*128 + uk)*512 + lane*8 + j] = ws[p][uv = uk*32 + (lane>>4)*8 + j][w = nt*16 + (lane&15)]
__global__ void prep_ws(const float* __restrict__ ws, f16* __restrict__ wsf) {
  int blk = blockIdx.x;            // 11*128 blocks
  int p = blk >> 7, uk = blk & 127;
  int tid = threadIdx.x;           // 256
  int nt = tid >> 6, l = tid & 63;
  int w = nt * 16 + (l & 15);
  int uvb = uk * 32 + (l >> 4) * 8;
  f16x8 v;
#pragma unroll
  for (int j = 0; j < 8; ++j)
    v[j] = (f16)ws[(size_t)p * 262144 + (size_t)(uvb + j) * 64 + w];
  *(f16x8*)(wsf + ((size_t)((p * 4 + nt) * 128 + uk)) * 512 + (size_t)l * 8) = v;
}

// ---------------- main kernel ----------------
__device__ __forceinline__ f32x4 mfma16(f16x8 a, f16x8 b, f32x4 c) {
  return __builtin_amdgcn_mfma_f32_16x16x32_f16(a, b, c, 0, 0, 0);
}

// One jj-window pass over this wave's 8 u's, both K-halves; wsf streamed once.
template <int L1, int L2, int L3, int PORIG, int COFF, int J0, int JW>
__device__ __forceinline__ void run_pass(
    const f16* __restrict__ x2t, const f16* __restrict__ x1t,
    const f16* __restrict__ wsf, const KC& kc,
    int lane, int nt, int uq, f32x4 (&o)[5]) {
  constexpr int d1 = 2 * L1 + 1, d2 = 2 * L2 + 1, d3 = 2 * L3 + 1;
  constexpr int IP = ipad(d1);
  const int brow = lane >> 4, bcol = lane & 15;

  // A fragments (x2), both ks, window jj's — ds_read_b128 each
  f16x8 af[2][JW];
#pragma unroll
  for (int ks = 0; ks < 2; ++ks)
#pragma unroll
    for (int jw = 0; jw < JW; ++jw)
      af[ks][jw] = *(const f16x8*)&x2t[soff2(L2) + ((J0 + jw) * 16 + bcol) * 72 + ks * 32 + brow * 8];

  f16x2 G[d1][JW][2];
#pragma unroll
  for (int i = 0; i < d1; ++i)
#pragma unroll
    for (int jw = 0; jw < JW; ++jw) {
      G[i][jw][0] = f16x2{(f16)0.f, (f16)0.f};
      G[i][jw][1] = f16x2{(f16)0.f, (f16)0.f};
    }

  const f16* wb = wsf + ((size_t)(PORIG * 4 + nt) * 128 + (size_t)uq * 16) * 512 + (size_t)lane * 8;
  const f16* xb = x1t + soff1(L1) + brow * (64 * IP + 8) + uq * 8 * IP;

  f16x8 bf0 = *(const f16x8*)(wb);
  f16x8 bf1 = *(const f16x8*)(wb + 512);

#pragma unroll 1
  for (int u = 0; u < 8; ++u) {
    f16x8 nbf0 = bf0, nbf1 = bf1;
    if (u < 7) {
      nbf0 = *(const f16x8*)(wb + (size_t)(u + 1) * 1024);
      nbf1 = *(const f16x8*)(wb + (size_t)(u + 1) * 1024 + 512);
    }
    // x1 for this u: i-major, 4 b's each, from padded LDS (vector reads, bcol-broadcast)
    f16x2 xl[d1], xh[d1];
    const f16* xp = xb + u * IP;
    if constexpr (d1 == 1) {
      f16x4 a = *(const f16x4*)xp;
      xl[0] = f16x2{a[0], a[1]}; xh[0] = f16x2{a[2], a[3]};
    } else if constexpr (d1 == 3) {
      f16x8 a = *(const f16x8*)xp;
      f16x4 b = *(const f16x4*)(xp + 8);
      xl[0] = f16x2{a[0], a[1]}; xh[0] = f16x2{a[2], a[3]};
      xl[1] = f16x2{a[4], a[5]}; xh[1] = f16x2{a[6], a[7]};
      xl[2] = f16x2{b[0], b[1]}; xh[2] = f16x2{b[2], b[3]};
    } else {
      f16x8 a = *(const f16x8*)xp;
      f16x8 b = *(const f16x8*)(xp + 8);
      f16x4 c = *(const f16x4*)(xp + 16);
      xl[0] = f16x2{a[0], a[1]}; xh[0] = f16x2{a[2], a[3]};
      xl[1] = f16x2{a[4], a[5]}; xh[1] = f16x2{a[6], a[7]};
      xl[2] = f16x2{b[0], b[1]}; xh[2] = f16x2{b[2], b[3]};
      xl[3] = f16x2{b[4], b[5]}; xh[3] = f16x2{b[6], b[7]};
      xl[4] = f16x2{c[0], c[1]}; xh[4] = f16x2{c[2], c[3]};
    }
#pragma unroll
    for (int ks = 0; ks < 2; ++ks) {
      f16x8 bf = ks ? bf1 : bf0;
#pragma unroll
      for (int jw = 0; jw < JW; ++jw) {
        f32x4 z{0.f, 0.f, 0.f, 0.f};
        f32x4 M = mfma16(af[ks][jw], bf, z);
        f16x2 Ml = pkrtz(M[0], M[1]);
        f16x2 Mh = pkrtz(M[2], M[3]);
#pragma unroll
        for (int i = 0; i < d1; ++i)
          if (pair_used(L1, L2, L3, i, J0 + jw)) {
            G[i][jw][0] += xl[i] * Ml;
            G[i][jw][1] += xh[i] * Mh;
          }
      }
    }
    bf0 = nbf0; bf1 = nbf1;
  }

  // C-mix once per pass: o[k3] += C[i,jj,k3] * G[i][jj]
#pragma unroll
  for (int i = 0; i < d1; ++i)
#pragma unroll
    for (int jw = 0; jw < JW; ++jw)
      if (pair_used(L1, L2, L3, i, J0 + jw)) {
        float g0 = (float)G[i][jw][0][0], g1 = (float)G[i][jw][0][1];
        float g2 = (float)G[i][jw][1][0], g3 = (float)G[i][jw][1][1];
#pragma unroll
        for (int k3 = 0; k3 < d3; ++k3)
          if (w3j_nz(L1, L2, L3, i, J0 + jw, k3)) {
            float cv = kc.c[COFF + (i * d2 + (J0 + jw)) * d3 + k3];
            o[k3][0] = fmaf(cv, g0, o[k3][0]);
            o[k3][1] = fmaf(cv, g1, o[k3][1]);
            o[k3][2] = fmaf(cv, g2, o[k3][2]);
            o[k3][3] = fmaf(cv, g3, o[k3][3]);
          }
      }
}

// reduce 8 wave-partials (4 slots + RMW) and store contiguous full lines
template <int L3, int OFF3>
__device__ __forceinline__ void store_group(float* __restrict__ out, float* rbuf,
                                            int b0, int tid, int lane, int nt, int uq,
                                            f32x4 (&o)[5]) {
  constexpr int d3 = 2 * L3 + 1;
  constexpr int RS = 16 * d3 + 4;   // row stride (floats), 16B-aligned, bank-spread
  constexpr int SS = 16 * RS;       // slot stride
  const int brow = lane >> 4, bcol = lane & 15;
  __syncthreads();                  // previous reduce done; o final
  if (uq < 4) {
    float* s = rbuf + uq * SS;
#pragma unroll
    for (int k3 = 0; k3 < d3; ++k3)
#pragma unroll
      for (int r = 0; r < 4; ++r)
        s[(brow * 4 + r) * RS + bcol * d3 + k3] = o[k3][r];
  }
  __syncthreads();
  if (uq >= 4) {
    float* s = rbuf + (uq - 4) * SS;
#pragma unroll
    for (int k3 = 0; k3 < d3; ++k3)
#pragma unroll
      for (int r = 0; r < 4; ++r)
        s[(brow * 4 + r) * RS + bcol * d3 + k3] += o[k3][r];
  }
  __syncthreads();
  constexpr int NT = 64 * d3;       // 16 rows × 4*d3 f32x4 chunks
  if (tid < NT) {
    int row = tid / (4 * d3);
    int c = tid - row * (4 * d3);
    f32x4 acc = *(const f32x4*)&rbuf[row * RS + c * 4];
#pragma unroll
    for (int sl = 1; sl < 4; ++sl)
      acc += *(const f32x4*)&rbuf[sl * SS + row * RS + c * 4];
    *(f32x4*)&out[(size_t)(b0 + row) * FEAT + OFF3 + nt * 16 * d3 + c * 4] = acc;
  }
#pragma unroll
  for (int k3 = 0; k3 < 5; ++k3) o[k3] = f32x4{0.f, 0.f, 0.f, 0.f};
}

__global__ __launch_bounds__(512, 4) void tp_main(
    const float* __restrict__ x1, const float* __restrict__ x2,
    const f16* __restrict__ wsf, float* __restrict__ out, KC kc) {
  __shared__ alignas(16) f16 x2t[10368];   // [jj-plane][b][v], 72-padded rows
  __shared__ alignas(16) f16 x1t[11360];   // [b4][u][i][4b], 8-padded sections
  __shared__ alignas(16) float rbuf[4 * 16 * 84];  // 21504 B (sized for d3=5)

  int tid = threadIdx.x;
  int lane = tid & 63, uq = tid >> 6;      // 8 waves = 8 u-slices of 8
  int blk = blockIdx.x;                    // 1024 blocks
  int xcd = blk & 7;                       // XCD pin: same nt per XCD-pair
  int nt = xcd >> 1;
  int btile = ((blk >> 3) << 1) | (xcd & 1);
  int b0 = btile * 16;

  // ---- stage x1, x2 (all 576 feats, 16 rows) once, transposed/padded ----
#pragma unroll 1
  for (int t = tid; t < 16 * 144; t += 512) {
    int b = t / 144, c = t - b * 144;
    f32x4 v1 = *(const f32x4*)&x1[(size_t)(b0 + b) * FEAT + 4 * c];
    f32x4 v2 = *(const f32x4*)&x2[(size_t)(b0 + b) * FEAT + 4 * c];
#pragma unroll
    for (int k = 0; k < 4; ++k) {
      int f = 4 * c + k;
      f16 e1 = (f16)v1[k], e2 = (f16)v2[k];
      if (f < 64) {
        int m = f;
        x2t[soff2(0) + b * 72 + m] = e2;
        x1t[soff1(0) + (b >> 2) * (64 * 4 + 8) + m * 4 + (b & 3)] = e1;
      } else if (f < 256) {
        int lf = f - 64, m = lf / 3, ii = lf - m * 3;
        x2t[soff2(1) + (ii * 16 + b) * 72 + m] = e2;
        x1t[soff1(1) + (b >> 2) * (64 * 16 + 8) + m * 16 + ii * 4 + (b & 3)] = e1;
      } else {
        int lf = f - 256, m = lf / 5, ii = lf - m * 5;
        x2t[soff2(2) + (ii * 16 + b) * 72 + m] = e2;
        x1t[soff1(2) + (b >> 2) * (64 * 24 + 8) + m * 24 + ii * 4 + (b & 3)] = e1;
      }
    }
  }
  __syncthreads();

  f32x4 o[5];
#pragma unroll
  for (int k = 0; k < 5; ++k) o[k] = f32x4{0.f, 0.f, 0.f, 0.f};

  // i3 = 0 group (out feats [0,64), d3=1)
  run_pass<0, 0, 0, 0, 0, 0, 1>(x2t, x1t, wsf, kc, lane, nt, uq, o);
  run_pass<1, 1, 0, 4, 44, 0, 3>(x2t, x1t, wsf, kc, lane, nt, uq, o);
  run_pass<2, 2, 0, 9, 213, 0, 3>(x2t, x1t, wsf, kc, lane, nt, uq, o);
  run_pass<2, 2, 0, 9, 213, 3, 2>(x2t, x1t, wsf, kc, lane, nt, uq, o);
  store_group<0, 0>(out, rbuf, b0, tid, lane, nt, uq, o);
  // i3 = 1 group (out feats [64,256), d3=3)
  run_pass<0, 1, 1, 1, 1, 0, 3>(x2t, x1t, wsf, kc, lane, nt, uq, o);
  run_pass<1, 0, 1, 3, 35, 0, 1>(x2t, x1t, wsf, kc, lane, nt, uq, o);
  run_pass<1, 2, 1, 6, 98, 0, 3>(x2t, x1t, wsf, kc, lane, nt, uq, o);
  run_pass<1, 2, 1, 6, 98, 3, 2>(x2t, x1t, wsf, kc, lane, nt, uq, o);
  run_pass<2, 1, 1, 8, 168, 0, 3>(x2t, x1t, wsf, kc, lane, nt, uq, o);
  store_group<1, 64>(out, rbuf, b0, tid, lane, nt, uq, o);
  // i3 = 2 group (out feats [256,576), d3=5)
  run_pass<0, 2, 2, 2, 10, 0, 5>(x2t, x1t, wsf, kc, lane, nt, uq, o);
  run_pass<1, 1, 2, 5, 53, 0, 3>(x2t, x1t, wsf, kc, lane, nt, uq, o);
  run_pass<2, 0, 2, 7, 143, 0, 1>(x2t, x1t, wsf, kc, lane, nt, uq, o);
  run_pass<2, 2, 2, 10, 238, 0, 3>(x2t, x1t, wsf, kc, lane, nt, uq, o);
  run_pass<2, 2, 2, 10, 238, 3, 2>(x2t, x1t, wsf, kc, lane, nt, uq, o);
  store_group<2, 256>(out, rbuf, b0, tid, lane, nt, uq, o);
}

// ---------------- host: exact port of reference Wigner-3j construction ----------------
static double factd(int n) { double r = 1; for (int i = 2; i <= n; ++i) r *= i; return r; }

static double su2_cg(int j1, int j2, int j3, int m1, int m2, int m3) {
  if (m1 + m2 != m3) return 0.0;
  double pre = std::sqrt((2 * j3 + 1) * factd(j1 + j2 - j3) * factd(j1 - j2 + j3) * factd(-j1 + j2 + j3) / factd(j1 + j2 + j3 + 1));
  pre *= std::sqrt(factd(j3 + m3) * factd(j3 - m3) * factd(j1 - m1) * factd(j1 + m1) * factd(j2 - m2) * factd(j2 + m2));
  double s = 0.0;
  for (int v = 0; v <= j1 + j2 - j3; ++v) {
    int t[6] = {v, j1 + j2 - j3 - v, j1 - m1 - v, j2 + m2 - v, j3 - j2 + m1 + v, j3 - j1 - m2 + v};
    bool ok = true;
    for (int x = 0; x < 6; ++x) if (t[x] < 0) ok = false;
    if (!ok) continue;
    double den = 1.0;
    for (int x = 0; x < 6; ++x) den *= factd(t[x]);
    s += ((v & 1) ? -1.0 : 1.0) / den;
  }
  return pre * s;
}

static void qmat(int l, std::complex<double> q[5][5]) {
  int n = 2 * l + 1;
  for (int i = 0; i < 5; ++i) for (int j = 0; j < 5; ++j) q[i][j] = 0.0;
  const double s = 1.0 / std::sqrt(2.0);
  for (int m = -l; m < 0; ++m) {
    q[l + m][l - m] = s;
    q[l + m][l + m] = std::complex<double>(0.0, -s);
  }
  q[l][l] = 1.0;
  for (int m = 1; m <= l; ++m) {
    double sg = (m % 2) ? -1.0 : 1.0;
    q[l + m][l + m] = sg * s;
    q[l + m][l - m] = std::complex<double>(0.0, sg * s);
  }
  std::complex<double> pref(1.0, 0.0);
  for (int t = 0; t < l; ++t) pref *= std::complex<double>(0.0, -1.0);
  for (int i = 0; i < n; ++i) for (int j = 0; j < n; ++j) q[i][j] *= pref;
}

static void compute_w3j(int l1, int l2, int l3, float* dst) {
  int n1 = 2 * l1 + 1, n2 = 2 * l2 + 1, n3 = 2 * l3 + 1;
  std::complex<double> q1[5][5], q2[5][5], q3[5][5];
  qmat(l1, q1); qmat(l2, q2); qmat(l3, q3);
  double nrm = 0.0;
  double C[5][5][5];
  for (int a = 0; a < n1; ++a)
    for (int b = 0; b < n2; ++b)
      for (int c = 0; c < n3; ++c) {
        std::complex<double> acc(0.0, 0.0);
        for (int i = 0; i < n1; ++i)
          for (int j = 0; j < n2; ++j)
            for (int k = 0; k < n3; ++k) {
              double cg = su2_cg(l1, l2, l3, i - l1, j - l2, k - l3);
              if (cg != 0.0) acc += q1[i][a] * q2[j][b] * std::conj(q3[k][c]) * cg;
            }
        C[a][b][c] = acc.real();
        nrm += acc.real() * acc.real();
      }
  double inv = 1.0 / std::sqrt(nrm);
  for (int a = 0; a < n1; ++a)
    for (int b = 0; b < n2; ++b)
      for (int c = 0; c < n3; ++c)
        dst[(a * n2 + b) * n3 + c] = (float)(C[a][b][c] * inv);
}

extern "C" void kernel_launch(void* const* d_in, const int* in_sizes, int n_in,
                              void* d_out, int out_size, void* d_ws, size_t ws_size,
                              hipStream_t stream) {
  const float* x1 = (const float*)d_in[0];
  const float* x2 = (const float*)d_in[1];
  const float* ws = (const float*)d_in[2];
  float* out = (float*)d_out;
  f16* wsf = (f16*)d_ws;

  KC kc;
  {
    static const int L1[11] = {0, 0, 0, 1, 1, 1, 1, 2, 2, 2, 2};
    static const int L2[11] = {0, 1, 2, 0, 1, 1, 2, 0, 1, 2, 2};
    static const int L3[11] = {0, 1, 2, 1, 0, 2, 1, 2, 1, 0, 2};
    static const int COFFS[11] = {0, 1, 10, 35, 44, 53, 98, 143, 168, 213, 238};
    for (int p = 0; p < 11; ++p) compute_w3j(L1[p], L2[p], L3[p], kc.c + COFFS[p]);
  }

  hipLaunchKernelGGL(prep_ws, dim3(11 * 128), dim3(256), 0, stream, ws, wsf);
  hipLaunchKernelGGL(tp_main, dim3(1024), dim3(512), 0, stream, x1, x2, wsf, out, kc);
}